// Round 2
// baseline (1111.882 us; speedup 1.0000x reference)
//
#include <hip/hip_runtime.h>
#include <math.h>

#define PI2 6.283185307179586f

// B=32, H=128, W=128, C=128; hm modes 32 (rows 0..15,112..127), k modes 17
// Layouts (float2 = complex):
//  kout0/kin0: [32][128][2][64]; kout1/kin1: [17][128][2][64]
//  S0: [32][128][128]{d0,d1} as float4   S1: [17][128][128] float4
//  Xw/Q: [32][128][17][128] f2   Xf/Y: [32][32][17][128] f2

// ---------------- S build: S[s,i,j,d] = sum_r ko[s,i,d,r]*ki[s,j,d,r] -------
__global__ __launch_bounds__(128) void k_S(
    const float2* __restrict__ ko0, const float2* __restrict__ ki0,
    const float2* __restrict__ ko1, const float2* __restrict__ ki1,
    float4* __restrict__ S0, float4* __restrict__ S1) {
  int bid = blockIdx.x;
  int s = bid >> 7;      // 0..48
  int i = bid & 127;
  int j = threadIdx.x;   // 128 threads
  const float2* ko; const float2* ki; float4* S; int si;
  if (s < 32) { ko = ko0; ki = ki0; S = S0; si = s; }
  else        { ko = ko1; ki = ki1; S = S1; si = s - 32; }
  __shared__ float2 koS[2][64];
  koS[j >> 6][j & 63] = ko[(si * 128 + i) * 128 + j];
  __syncthreads();
  const float2* kirow = ki + (si * 128 + j) * 128;
  float2 acc[2];
#pragma unroll
  for (int d = 0; d < 2; d++) {
    float2 a2 = make_float2(0.f, 0.f);
    for (int r = 0; r < 64; r++) {
      float2 a = koS[d][r];
      float2 b = kirow[d * 64 + r];
      a2.x += a.x * b.x - a.y * b.y;
      a2.y += a.x * b.y + a.y * b.x;
    }
    acc[d] = a2;
  }
  S[(si * 128 + i) * 128 + j] = make_float4(acc[0].x, acc[0].y, acc[1].x, acc[1].y);
}

// ---------------- F1: Xw[b,y,k,c] = sc * sum_x X[b,y,x,c] e^{-i 2pi kx/128} -
// 4 y-rows per block + distance-1 register prefetch (hides global load latency)
// + incremental twiddle byte-offsets (ob += 8k mod 1024; no per-iter mul).
__global__ __launch_bounds__(256) void k_F1(
    const float* __restrict__ X, float2* __restrict__ Xw) {
  __shared__ float2 tw[128];
  int t = threadIdx.x;
  if (t < 128) { float s, c; __sincosf(PI2 * t / 128.f, &s, &c); tw[t] = make_float2(c, s); }
  __syncthreads();
  const char* twc = (const char*)tw;
  int c = t & 127, kg = t >> 7;
  int b = blockIdx.x >> 5;
  int y0 = (blockIdx.x & 31) * 4;
  const float* xr = X + ((size_t)(b * 128 + y0) * 128) * 128 + c;
  float2 a[4][9];
  int ob[9];
  const int kb8 = kg * 72;   // 8 * (kg*9)
#pragma unroll
  for (int kk = 0; kk < 9; kk++) {
    ob[kk] = 0;
#pragma unroll
    for (int r = 0; r < 4; r++) a[r][kk] = make_float2(0.f, 0.f);
  }
  float v0 = xr[0], v1 = xr[16384], v2 = xr[32768], v3 = xr[49152];
  for (int x = 0; x < 128; x++) {
    int xn = ((x + 1) & 127) * 128;   // wrap: last iter re-reads x=0 (cached, discarded)
    float f0 = xr[xn];
    float f1 = xr[16384 + xn];
    float f2 = xr[32768 + xn];
    float f3 = xr[49152 + xn];
#pragma unroll
    for (int kk = 0; kk < 9; kk++) {
      float2 w = *(const float2*)(twc + ob[kk]);
      ob[kk] = (ob[kk] + kb8 + kk * 8) & 1016;   // exact: step<1024, vals mult of 8
      a[0][kk].x += v0 * w.x; a[0][kk].y -= v0 * w.y;
      a[1][kk].x += v1 * w.x; a[1][kk].y -= v1 * w.y;
      a[2][kk].x += v2 * w.x; a[2][kk].y -= v2 * w.y;
      a[3][kk].x += v3 * w.x; a[3][kk].y -= v3 * w.y;
    }
    v0 = f0; v1 = f1; v2 = f2; v3 = f3;
  }
  const float sc = 1.f / 16384.f;
  float2* o0 = Xw + ((size_t)(b * 128 + y0) * 17) * 128 + c;
#pragma unroll
  for (int r = 0; r < 4; r++) {
#pragma unroll
    for (int kk = 0; kk < 9; kk++) {
      int k = kg * 9 + kk;
      if (k < 17)
        o0[r * 2176 + k * 128] = make_float2(a[r][kk].x * sc, a[r][kk].y * sc);
    }
  }
}

// ---------------- F2: Xf[b,hm,k,c] = sum_y Xw[b,y,k,c] e^{-i 2pi h y/128} ---
// half-block hh handles hm = hh*16 .. hh*16+15; distance-1 prefetch on the
// strided global read + incremental twiddle offsets.
__global__ __launch_bounds__(256) void k_F2(
    const float2* __restrict__ Xw, float2* __restrict__ Xf) {
  __shared__ float2 tw[128];
  int t = threadIdx.x;
  if (t < 128) { float s, c; __sincosf(PI2 * t / 128.f, &s, &c); tw[t] = make_float2(c, s); }
  __syncthreads();
  const char* twc = (const char*)tw;
  int b = blockIdx.x / 17, k = blockIdx.x - b * 17;
  int c = t & 127, hh = t >> 7;
  float2 acc[16];
  int ob[16];
#pragma unroll
  for (int q = 0; q < 16; q++) { acc[q] = make_float2(0.f, 0.f); ob[q] = 0; }
  const int hb8 = hh ? 896 : 0;  // 8*112; h = hm (hm<16) or hm+96; hm = hh*16+q
  const float2* xp = Xw + ((size_t)(b * 128) * 17 + k) * 128 + c;
  float2 xv = xp[0];
  for (int y = 0; y < 128; y++) {
    float2 xn = xp[(size_t)((y + 1) & 127) * 2176];
#pragma unroll
    for (int q = 0; q < 16; q++) {
      float2 w = *(const float2*)(twc + ob[q]);
      ob[q] = (ob[q] + hb8 + q * 8) & 1016;
      acc[q].x += xv.x * w.x + xv.y * w.y;
      acc[q].y += xv.y * w.x - xv.x * w.y;
    }
    xv = xn;
  }
  float2* op = Xf + ((size_t)(b * 32 + hh * 16) * 17 + k) * 128 + c;
#pragma unroll
  for (int q = 0; q < 16; q++) op[(size_t)q * 2176] = acc[q];
}

// ---------------- spec (fused K): Y[b,m,i] = sum_j K[m,i,j] Xf[b,m,j] -------
// K[m,i,j] = sum_d S0[hm,i,j,d]*S1[w,i,j,d], computed in the staging step.
__global__ __launch_bounds__(256) void k_spec(
    const float4* __restrict__ S0, const float4* __restrict__ S1,
    const float2* __restrict__ Xf, float2* __restrict__ Y) {
  __shared__ float2 Xs[32][128];
  __shared__ float2 Ks[16][129];
  int m = blockIdx.x;
  int hm = m / 17, w = m - hm * 17;
  int t = threadIdx.x;
  for (int q = t; q < 32 * 128; q += 256) {
    int b = q >> 7, j = q & 127;
    Xs[b][j] = Xf[((size_t)(b * 32 + hm) * 17 + w) * 128 + j];
  }
  const float4* s0p = S0 + (size_t)hm * 16384;
  const float4* s1p = S1 + (size_t)w * 16384;
  int i = t & 127, bh = t >> 7;
  float2 acc[16];
#pragma unroll
  for (int bb = 0; bb < 16; bb++) acc[bb] = make_float2(0.f, 0.f);
  for (int jt = 0; jt < 128; jt += 16) {
    __syncthreads();
    for (int q = t; q < 16 * 128; q += 256) {
      int ii = q >> 4, jj = q & 15;
      float4 a = s0p[ii * 128 + jt + jj];
      float4 b4 = s1p[ii * 128 + jt + jj];
      Ks[jj][ii] = make_float2(a.x * b4.x - a.y * b4.y + a.z * b4.z - a.w * b4.w,
                               a.x * b4.y + a.y * b4.x + a.z * b4.w + a.w * b4.z);
    }
    __syncthreads();
#pragma unroll 4
    for (int jj = 0; jj < 16; jj++) {
      float2 kv = Ks[jj][i];
#pragma unroll
      for (int bb = 0; bb < 16; bb++) {
        float2 xv = Xs[bh * 16 + bb][jt + jj];
        acc[bb].x += kv.x * xv.x - kv.y * xv.y;
        acc[bb].y += kv.x * xv.y + kv.y * xv.x;
      }
    }
  }
#pragma unroll
  for (int bb = 0; bb < 16; bb++) {
    int b = bh * 16 + bb;
    Y[((size_t)(b * 32 + hm) * 17 + w) * 128 + i] = acc[bb];
  }
}

// ---------------- I1: Q[b,y,k,o] = sum_hm Y[b,hm,k,o] e^{+i 2pi h y/128} ----
// Y values held in 32 complex registers; incremental twiddle offsets.
__global__ __launch_bounds__(256) void k_I1(
    const float2* __restrict__ Y, float2* __restrict__ Q) {
  __shared__ float2 tw[128];
  int t = threadIdx.x;
  if (t < 128) { float s, c; __sincosf(PI2 * t / 128.f, &s, &c); tw[t] = make_float2(c, s); }
  __syncthreads();
  const char* twc = (const char*)tw;
  int b = blockIdx.x / 17, k = blockIdx.x - b * 17;
  int o = t & 127, yh = t >> 7;
  float2 v[32];
  int ob[32];
#pragma unroll
  for (int hm = 0; hm < 32; hm++) {
    v[hm] = Y[((size_t)(b * 32 + hm) * 17 + k) * 128 + o];
    int h8 = (hm < 16 ? hm : hm + 96) * 8;
    ob[hm] = (h8 * (yh * 64)) & 1016;
  }
  float2* qp = Q + ((size_t)(b * 128) * 17 + k) * 128 + o;
  for (int yy = 0; yy < 64; yy++) {
    int y = yh * 64 + yy;
    float2 a = make_float2(0.f, 0.f);
#pragma unroll
    for (int hm = 0; hm < 32; hm++) {
      float2 w = *(const float2*)(twc + ob[hm]);
      const int h8 = (hm < 16 ? hm : hm + 96) * 8;
      ob[hm] = (ob[hm] + h8) & 1016;
      a.x += v[hm].x * w.x - v[hm].y * w.y;
      a.y += v[hm].x * w.y + v[hm].y * w.x;
    }
    qp[(size_t)y * 2176] = a;
  }
}

// ---------------- I2: out[b,y,x,o] = sum_k wk Re(Q[b,y,k,o] e^{+i 2pi kx/128})
// 2 y-rows per block; Q held in 2x17 complex registers (weight folded in).
__global__ __launch_bounds__(256) void k_I2(
    const float2* __restrict__ Q, float* __restrict__ out) {
  __shared__ float2 tw[128];
  int t = threadIdx.x;
  if (t < 128) { float s, c; __sincosf(PI2 * t / 128.f, &s, &c); tw[t] = make_float2(c, s); }
  __syncthreads();
  const char* twc = (const char*)tw;
  int b = blockIdx.x >> 6;
  int y0 = (blockIdx.x & 63) * 2;
  int o = t & 127, xh = t >> 7;
  const float2* q0p = Q + ((size_t)(b * 128 + y0) * 17) * 128 + o;
  float2 q0[17], q1[17];
#pragma unroll
  for (int k = 0; k < 17; k++) {
    float wgt = (k == 0) ? 1.f : 2.f;
    float2 v0 = q0p[k * 128];
    float2 v1 = q0p[2176 + k * 128];
    q0[k] = make_float2(v0.x * wgt, v0.y * wgt);
    q1[k] = make_float2(v1.x * wgt, v1.y * wgt);
  }
  float* o0 = out + ((size_t)(b * 128 + y0) * 128) * 128 + o;
  float* o1 = o0 + 16384;
  for (int xx = 0; xx < 64; xx++) {
    int x = xh * 64 + xx;
    float s0 = 0.f, s1 = 0.f;
#pragma unroll
    for (int k = 0; k < 17; k++) {
      int ob = (k * 8 * x) & 1016;
      float2 w = *(const float2*)(twc + ob);
      s0 += q0[k].x * w.x - q0[k].y * w.y;
      s1 += q1[k].x * w.x - q1[k].y * w.y;
    }
    o0[x * 128] = s0;
    o1[x * 128] = s1;
  }
}

extern "C" void kernel_launch(void* const* d_in, const int* in_sizes, int n_in,
                              void* d_out, int out_size, void* d_ws, size_t ws_size,
                              hipStream_t stream) {
  (void)in_sizes; (void)n_in; (void)out_size;
  const float*  X     = (const float*)d_in[0];
  const float2* kout0 = (const float2*)d_in[1];
  const float2* kin0  = (const float2*)d_in[2];
  const float2* kout1 = (const float2*)d_in[3];
  const float2* kin1  = (const float2*)d_in[4];
  float* out = (float*)d_out;

  // Workspace (float2 units): A (Xw, reused as Q) | S0 | S1 | Xf | Y  = ~120 MB
  float2* ws = (float2*)d_ws;
  const size_t NA = 8912896;                 // 32*128*17*128
  float2* A  = ws;
  float2* S0 = ws + NA;                      // 1,048,576 f2 (as float4: 524,288)
  float2* S1 = S0 + 1048576;                 //   557,056 f2
  float2* Xf = S1 + 557056;                  // 2,228,224 f2
  float2* Yk = Xf + 2228224;                 // 2,228,224 f2
  const size_t need = (NA + 1048576 + 557056 + 2 * 2228224) * sizeof(float2);
  if (ws_size < need) return;

  k_S   <<<49 * 128, 128, 0, stream>>>(kout0, kin0, kout1, kin1,
                                       (float4*)S0, (float4*)S1);
  k_F1  <<<32 * 32, 256, 0, stream>>>(X, A);
  k_F2  <<<32 * 17, 256, 0, stream>>>(A, Xf);
  k_spec<<<544, 256, 0, stream>>>((const float4*)S0, (const float4*)S1, Xf, Yk);
  k_I1  <<<32 * 17, 256, 0, stream>>>(Yk, A);
  k_I2  <<<32 * 64, 256, 0, stream>>>(A, out);
}

// Round 3
// 1017.979 us; speedup vs baseline: 1.0922x; 1.0922x over previous
//
#include <hip/hip_runtime.h>
#include <math.h>

#define PI2 6.283185307179586f

// B=32, H=128, W=128, C=128; hm modes 32 (rows 0..15,112..127), k modes 17
// Layouts (float2 = complex):
//  kout0/kin0: [32][128][2][64]; kout1/kin1: [17][128][2][64]
//  S0: [32][128][128]{d0,d1} as float4   S1: [17][128][128] float4
//  Xw/Q: [32][128][17][128] f2   Xf/Y: [32][32][17][128] f2

// ---------------- S build: S[s,i,j,d] = sum_r ko[s,i,d,r]*ki[s,j,d,r] -------
__global__ __launch_bounds__(128) void k_S(
    const float2* __restrict__ ko0, const float2* __restrict__ ki0,
    const float2* __restrict__ ko1, const float2* __restrict__ ki1,
    float4* __restrict__ S0, float4* __restrict__ S1) {
  int bid = blockIdx.x;
  int s = bid >> 7;      // 0..48
  int i = bid & 127;
  int j = threadIdx.x;   // 128 threads
  const float2* ko; const float2* ki; float4* S; int si;
  if (s < 32) { ko = ko0; ki = ki0; S = S0; si = s; }
  else        { ko = ko1; ki = ki1; S = S1; si = s - 32; }
  __shared__ float2 koS[2][64];
  koS[j >> 6][j & 63] = ko[(si * 128 + i) * 128 + j];
  __syncthreads();
  const float2* kirow = ki + (si * 128 + j) * 128;
  float2 acc[2];
#pragma unroll
  for (int d = 0; d < 2; d++) {
    float2 a2 = make_float2(0.f, 0.f);
    for (int r = 0; r < 64; r++) {
      float2 a = koS[d][r];
      float2 b = kirow[d * 64 + r];
      a2.x += a.x * b.x - a.y * b.y;
      a2.y += a.x * b.y + a.y * b.x;
    }
    acc[d] = a2;
  }
  S[(si * 128 + i) * 128 + j] = make_float4(acc[0].x, acc[0].y, acc[1].x, acc[1].y);
}

// ---------------- F1: Xw[b,y,k,c] = sc * sum_x X[b,y,x,c] e^{-i 2pi kx/128} -
// R0 grid shape (2048 blocks, 8 waves/SIMD) but channel-pair vectorized:
// thread owns float2 c-pair; k split 4-ways across waves (k = kg + 4*kk).
// Each twiddle ds_read feeds 8 FMAs; ~0.5x total instructions vs R0.
__global__ __launch_bounds__(256) void k_F1(
    const float* __restrict__ X, float2* __restrict__ Xw) {
  __shared__ float2 tw[128];
  int t = threadIdx.x;
  if (t < 128) { float s, c; __sincosf(PI2 * t / 128.f, &s, &c); tw[t] = make_float2(c, s); }
  __syncthreads();
  const char* twc = (const char*)tw;
  int cp = t & 63, kg = t >> 6;          // kg wave-uniform (4 groups)
  int b = blockIdx.x >> 6;
  int y0 = (blockIdx.x & 63) * 2;
  const float2* x0 = (const float2*)X + ((size_t)(b * 128 + y0) * 128) * 64 + cp;
  float2 a[2][5][2];
#pragma unroll
  for (int r = 0; r < 2; r++)
#pragma unroll
    for (int kk = 0; kk < 5; kk++) {
      a[r][kk][0] = make_float2(0.f, 0.f);
      a[r][kk][1] = make_float2(0.f, 0.f);
    }
  for (int x = 0; x < 128; x++) {
    float2 v0 = x0[x * 64];
    float2 v1 = x0[8192 + x * 64];
#pragma unroll
    for (int kk = 0; kk < 5; kk++) {
      if (kk < 4 || kg == 0) {           // k = kg+4*kk; only kg=0 has kk=4 (k=16)
        int k8 = (kg + 4 * kk) * 8;
        int ob = (k8 * x) & 1016;        // wave-uniform -> SALU + broadcast ds_read
        float2 w = *(const float2*)(twc + ob);
        a[0][kk][0].x += v0.x * w.x; a[0][kk][0].y -= v0.x * w.y;
        a[0][kk][1].x += v0.y * w.x; a[0][kk][1].y -= v0.y * w.y;
        a[1][kk][0].x += v1.x * w.x; a[1][kk][0].y -= v1.x * w.y;
        a[1][kk][1].x += v1.y * w.x; a[1][kk][1].y -= v1.y * w.y;
      }
    }
  }
  const float sc = 1.f / 16384.f;
#pragma unroll
  for (int r = 0; r < 2; r++) {
#pragma unroll
    for (int kk = 0; kk < 5; kk++) {
      if (kk < 4 || kg == 0) {
        int k = kg + 4 * kk;
        float4* dst = (float4*)(Xw + ((size_t)((b * 128 + y0 + r) * 17 + k)) * 128 + 2 * cp);
        *dst = make_float4(a[r][kk][0].x * sc, a[r][kk][0].y * sc,
                           a[r][kk][1].x * sc, a[r][kk][1].y * sc);
      }
    }
  }
}

// ---------------- F2: Xf[b,hm,k,c] = sum_y Xw[b,y,k,c] e^{-i 2pi h y/128} ---
// Grid doubled (mode-split): each block handles 16 of the 32 hm modes
// (8 per thread) -> 1088 blocks, 4.25 waves/SIMD for latency hiding.
__global__ __launch_bounds__(256) void k_F2(
    const float2* __restrict__ Xw, float2* __restrict__ Xf) {
  __shared__ float2 tw[128];
  int t = threadIdx.x;
  if (t < 128) { float s, c; __sincosf(PI2 * t / 128.f, &s, &c); tw[t] = make_float2(c, s); }
  __syncthreads();
  const char* twc = (const char*)tw;
  int bk = blockIdx.x >> 1, mh = blockIdx.x & 1;
  int b = bk / 17, k = bk - b * 17;
  int c = t & 127, hh = t >> 7;
  int g = mh * 2 + hh;                    // mode group 0..3: hm = g*8 + q
  int h8[8];
#pragma unroll
  for (int q = 0; q < 8; q++) {
    int hm = g * 8 + q;
    h8[q] = (hm < 16 ? hm : hm + 96) * 8;
  }
  float2 acc[8];
#pragma unroll
  for (int q = 0; q < 8; q++) acc[q] = make_float2(0.f, 0.f);
  const float2* xp = Xw + ((size_t)(b * 128) * 17 + k) * 128 + c;
  for (int y = 0; y < 128; y++) {
    float2 xv = xp[(size_t)y * 2176];
#pragma unroll
    for (int q = 0; q < 8; q++) {
      int ob = (h8[q] * y) & 1016;
      float2 w = *(const float2*)(twc + ob);
      acc[q].x += xv.x * w.x + xv.y * w.y;
      acc[q].y += xv.y * w.x - xv.x * w.y;
    }
  }
  float2* op = Xf + ((size_t)(b * 32 + g * 8) * 17 + k) * 128 + c;
#pragma unroll
  for (int q = 0; q < 8; q++) op[(size_t)q * 2176] = acc[q];
}

// ---------------- spec (fused K): Y[b,m,i] = sum_j K[m,i,j] Xf[b,m,j] -------
// K[m,i,j] = sum_d S0[hm,i,j,d]*S1[w,i,j,d], computed in the staging step.
__global__ __launch_bounds__(256) void k_spec(
    const float4* __restrict__ S0, const float4* __restrict__ S1,
    const float2* __restrict__ Xf, float2* __restrict__ Y) {
  __shared__ float2 Xs[32][128];
  __shared__ float2 Ks[16][129];
  int m = blockIdx.x;
  int hm = m / 17, w = m - hm * 17;
  int t = threadIdx.x;
  for (int q = t; q < 32 * 128; q += 256) {
    int b = q >> 7, j = q & 127;
    Xs[b][j] = Xf[((size_t)(b * 32 + hm) * 17 + w) * 128 + j];
  }
  const float4* s0p = S0 + (size_t)hm * 16384;
  const float4* s1p = S1 + (size_t)w * 16384;
  int i = t & 127, bh = t >> 7;
  float2 acc[16];
#pragma unroll
  for (int bb = 0; bb < 16; bb++) acc[bb] = make_float2(0.f, 0.f);
  for (int jt = 0; jt < 128; jt += 16) {
    __syncthreads();
    for (int q = t; q < 16 * 128; q += 256) {
      int ii = q >> 4, jj = q & 15;
      float4 a = s0p[ii * 128 + jt + jj];
      float4 b4 = s1p[ii * 128 + jt + jj];
      Ks[jj][ii] = make_float2(a.x * b4.x - a.y * b4.y + a.z * b4.z - a.w * b4.w,
                               a.x * b4.y + a.y * b4.x + a.z * b4.w + a.w * b4.z);
    }
    __syncthreads();
#pragma unroll 4
    for (int jj = 0; jj < 16; jj++) {
      float2 kv = Ks[jj][i];
#pragma unroll
      for (int bb = 0; bb < 16; bb++) {
        float2 xv = Xs[bh * 16 + bb][jt + jj];
        acc[bb].x += kv.x * xv.x - kv.y * xv.y;
        acc[bb].y += kv.x * xv.y + kv.y * xv.x;
      }
    }
  }
#pragma unroll
  for (int bb = 0; bb < 16; bb++) {
    int b = bh * 16 + bb;
    Y[((size_t)(b * 32 + hm) * 17 + w) * 128 + i] = acc[bb];
  }
}

// ---------------- I1: Q[b,y,k,o] = sum_hm Y[b,hm,k,o] e^{+i 2pi h y/128} ----
// Grid doubled (y-split): each block covers 64 y (32 per thread) -> 1088
// blocks, reaching the VGPR-allowed ~4 waves/SIMD.
__global__ __launch_bounds__(256) void k_I1(
    const float2* __restrict__ Y, float2* __restrict__ Q) {
  __shared__ float2 tw[128];
  int t = threadIdx.x;
  if (t < 128) { float s, c; __sincosf(PI2 * t / 128.f, &s, &c); tw[t] = make_float2(c, s); }
  __syncthreads();
  const char* twc = (const char*)tw;
  int bk = blockIdx.x >> 1, yq = blockIdx.x & 1;
  int b = bk / 17, k = bk - b * 17;
  int o = t & 127, yh = t >> 7;
  int ybase = yq * 64 + yh * 32;
  float2 v[32];
#pragma unroll
  for (int hm = 0; hm < 32; hm++)
    v[hm] = Y[((size_t)(b * 32 + hm) * 17 + k) * 128 + o];
  float2* qp = Q + ((size_t)(b * 128) * 17 + k) * 128 + o;
  for (int yy = 0; yy < 32; yy++) {
    int y = ybase + yy;
    float2 a = make_float2(0.f, 0.f);
#pragma unroll
    for (int hm = 0; hm < 32; hm++) {
      const int h8 = (hm < 16 ? hm : hm + 96) * 8;
      int ob = (h8 * y) & 1016;
      float2 w = *(const float2*)(twc + ob);
      a.x += v[hm].x * w.x - v[hm].y * w.y;
      a.y += v[hm].x * w.y + v[hm].y * w.x;
    }
    qp[(size_t)y * 2176] = a;
  }
}

// ---------------- I2: out[b,y,x,o] = sum_k wk Re(Q[b,y,k,o] e^{+i 2pi kx/128})
// 2 y-rows per block; Q held in 2x17 complex registers (weight folded in).
__global__ __launch_bounds__(256) void k_I2(
    const float2* __restrict__ Q, float* __restrict__ out) {
  __shared__ float2 tw[128];
  int t = threadIdx.x;
  if (t < 128) { float s, c; __sincosf(PI2 * t / 128.f, &s, &c); tw[t] = make_float2(c, s); }
  __syncthreads();
  const char* twc = (const char*)tw;
  int b = blockIdx.x >> 6;
  int y0 = (blockIdx.x & 63) * 2;
  int o = t & 127, xh = t >> 7;
  const float2* q0p = Q + ((size_t)(b * 128 + y0) * 17) * 128 + o;
  float2 q0[17], q1[17];
#pragma unroll
  for (int k = 0; k < 17; k++) {
    float wgt = (k == 0) ? 1.f : 2.f;
    float2 v0 = q0p[k * 128];
    float2 v1 = q0p[2176 + k * 128];
    q0[k] = make_float2(v0.x * wgt, v0.y * wgt);
    q1[k] = make_float2(v1.x * wgt, v1.y * wgt);
  }
  float* o0 = out + ((size_t)(b * 128 + y0) * 128) * 128 + o;
  float* o1 = o0 + 16384;
  for (int xx = 0; xx < 64; xx++) {
    int x = xh * 64 + xx;
    float s0 = 0.f, s1 = 0.f;
#pragma unroll
    for (int k = 0; k < 17; k++) {
      int ob = (k * 8 * x) & 1016;
      float2 w = *(const float2*)(twc + ob);
      s0 += q0[k].x * w.x - q0[k].y * w.y;
      s1 += q1[k].x * w.x - q1[k].y * w.y;
    }
    o0[x * 128] = s0;
    o1[x * 128] = s1;
  }
}

extern "C" void kernel_launch(void* const* d_in, const int* in_sizes, int n_in,
                              void* d_out, int out_size, void* d_ws, size_t ws_size,
                              hipStream_t stream) {
  (void)in_sizes; (void)n_in; (void)out_size;
  const float*  X     = (const float*)d_in[0];
  const float2* kout0 = (const float2*)d_in[1];
  const float2* kin0  = (const float2*)d_in[2];
  const float2* kout1 = (const float2*)d_in[3];
  const float2* kin1  = (const float2*)d_in[4];
  float* out = (float*)d_out;

  // Workspace (float2 units): A (Xw, reused as Q) | S0 | S1 | Xf | Y  = ~120 MB
  float2* ws = (float2*)d_ws;
  const size_t NA = 8912896;                 // 32*128*17*128
  float2* A  = ws;
  float2* S0 = ws + NA;                      // 1,048,576 f2 (as float4: 524,288)
  float2* S1 = S0 + 1048576;                 //   557,056 f2
  float2* Xf = S1 + 557056;                  // 2,228,224 f2
  float2* Yk = Xf + 2228224;                 // 2,228,224 f2
  const size_t need = (NA + 1048576 + 557056 + 2 * 2228224) * sizeof(float2);
  if (ws_size < need) return;

  k_S   <<<49 * 128, 128, 0, stream>>>(kout0, kin0, kout1, kin1,
                                       (float4*)S0, (float4*)S1);
  k_F1  <<<32 * 64, 256, 0, stream>>>(X, A);
  k_F2  <<<32 * 17 * 2, 256, 0, stream>>>(A, Xf);
  k_spec<<<544, 256, 0, stream>>>((const float4*)S0, (const float4*)S1, Xf, Yk);
  k_I1  <<<32 * 17 * 2, 256, 0, stream>>>(Yk, A);
  k_I2  <<<32 * 64, 256, 0, stream>>>(A, out);
}

// Round 4
// 943.488 us; speedup vs baseline: 1.1785x; 1.0790x over previous
//
#include <hip/hip_runtime.h>
#include <math.h>

#define PI2 6.283185307179586f

// B=32, H=128, W=128, C=128; hm modes 32 (rows 0..15,112..127), k modes 17
// Layouts (float2 = complex):
//  kout0/kin0: [32][128][2][64]; kout1/kin1: [17][128][2][64]
//  S0: [32][128][128]{d0,d1} as float4   S1: [17][128][128] float4
//  Xw/Q: [32][128][17][128] f2   Xf/Y: [32][32][17][128] f2

// ---------------- S build: S[s,i,j,d] = sum_r ko[s,i,d,r]*ki[s,j,d,r] -------
__global__ __launch_bounds__(128) void k_S(
    const float2* __restrict__ ko0, const float2* __restrict__ ki0,
    const float2* __restrict__ ko1, const float2* __restrict__ ki1,
    float4* __restrict__ S0, float4* __restrict__ S1) {
  int bid = blockIdx.x;
  int s = bid >> 7;      // 0..48
  int i = bid & 127;
  int j = threadIdx.x;   // 128 threads
  const float2* ko; const float2* ki; float4* S; int si;
  if (s < 32) { ko = ko0; ki = ki0; S = S0; si = s; }
  else        { ko = ko1; ki = ki1; S = S1; si = s - 32; }
  __shared__ float2 koS[2][64];
  koS[j >> 6][j & 63] = ko[(si * 128 + i) * 128 + j];
  __syncthreads();
  const float2* kirow = ki + (si * 128 + j) * 128;
  float2 acc[2];
#pragma unroll
  for (int d = 0; d < 2; d++) {
    float2 a2 = make_float2(0.f, 0.f);
    for (int r = 0; r < 64; r++) {
      float2 a = koS[d][r];
      float2 b = kirow[d * 64 + r];
      a2.x += a.x * b.x - a.y * b.y;
      a2.y += a.x * b.y + a.y * b.x;
    }
    acc[d] = a2;
  }
  S[(si * 128 + i) * 128 + j] = make_float4(acc[0].x, acc[0].y, acc[1].x, acc[1].y);
}

// ---------------- F1: Xw[b,y,k,c] = sc * sum_x X[b,y,x,c] e^{-i 2pi kx/128} -
// Thread owns a c-pair (float2); k split 4-ways across waves (k = kg + 4*kk).
// x processed in groups of 8 with ping-pong register prefetch (16 dwordx2 in
// flight, issued a full compute phase ahead) -> load latency hidden by ILP.
// Twiddle table stores (cos, -sin) duplicated to 256 entries so each
// accumulate is acc.xy += v * w.xy (v_pk_fma_f32 shape) with small-offset
// address chains (no per-read mod).
__global__ __launch_bounds__(256) void k_F1(
    const float* __restrict__ X, float2* __restrict__ Xw) {
  __shared__ float2 tw[256];                  // (cos, -sin), period-128 doubled
  int t = threadIdx.x;
  int cp = t & 63, kg = t >> 6;               // kg wave-uniform (4 groups)
  int b = blockIdx.x >> 6;
  int y0 = (blockIdx.x & 63) * 2;
  const float2* pA0 = (const float2*)X + ((size_t)(b * 128 + y0) * 128) * 64 + cp;
  const float2* pA1 = pA0 + 8192;             // row y0+1
  const float2* pB0 = pA0 + 512;              // group g+1
  const float2* pB1 = pA1 + 512;

  // Prologue: issue group-0 loads before the LDS init/barrier (overlap).
  float2 U0[8], U1[8], V0[8], V1[8];
#pragma unroll
  for (int j = 0; j < 8; j++) { U0[j] = pA0[j * 64]; U1[j] = pA1[j * 64]; }

  if (t < 128) {
    float s, c; __sincosf(PI2 * t / 128.f, &s, &c);
    tw[t] = make_float2(c, -s);
    tw[t + 128] = make_float2(c, -s);
  }
  __syncthreads();
  const char* twc = (const char*)tw;

  float2 a[2][5][2];
#pragma unroll
  for (int r = 0; r < 2; r++)
#pragma unroll
    for (int kk = 0; kk < 5; kk++) {
      a[r][kk][0] = make_float2(0.f, 0.f);
      a[r][kk][1] = make_float2(0.f, 0.f);
    }

  // One group's accumulation from buffers B0/B1 at x = xs..xs+7.
#define F1_COMPUTE(B0, B1, xs)                                            \
  {                                                                       \
    _Pragma("unroll")                                                     \
    for (int kk = 0; kk < 4; kk++) {                                      \
      int k8 = kg * 8 + 32 * kk;                                          \
      int ob = (k8 * (xs)) & 1016;                                        \
      _Pragma("unroll")                                                   \
      for (int j = 0; j < 8; j++) {                                       \
        float2 w = *(const float2*)(twc + ob + j * k8);                   \
        a[0][kk][0].x += B0[j].x * w.x; a[0][kk][0].y += B0[j].x * w.y;   \
        a[0][kk][1].x += B0[j].y * w.x; a[0][kk][1].y += B0[j].y * w.y;   \
        a[1][kk][0].x += B1[j].x * w.x; a[1][kk][0].y += B1[j].x * w.y;   \
        a[1][kk][1].x += B1[j].y * w.x; a[1][kk][1].y += B1[j].y * w.y;   \
      }                                                                   \
    }                                                                     \
    if (kg == 0) { /* wave-uniform: only wave 0 runs k=16 */              \
      int ob = (128 * (xs)) & 1016;                                       \
      _Pragma("unroll")                                                   \
      for (int j = 0; j < 8; j++) {                                       \
        float2 w = *(const float2*)(twc + ob + j * 128);                  \
        a[0][4][0].x += B0[j].x * w.x; a[0][4][0].y += B0[j].x * w.y;     \
        a[0][4][1].x += B0[j].y * w.x; a[0][4][1].y += B0[j].y * w.y;     \
        a[1][4][0].x += B1[j].x * w.x; a[1][4][0].y += B1[j].x * w.y;     \
        a[1][4][1].x += B1[j].y * w.x; a[1][4][1].y += B1[j].y * w.y;     \
      }                                                                   \
    }                                                                     \
  }

  for (int g = 0; g < 16; g += 2) {
    // prefetch group g+1
#pragma unroll
    for (int j = 0; j < 8; j++) { V0[j] = pB0[j * 64]; V1[j] = pB1[j * 64]; }
    F1_COMPUTE(U0, U1, g * 8)
    pA0 += 1024; pA1 += 1024; pB0 += 1024; pB1 += 1024;
    if (g < 14) {   // prefetch group g+2 (uniform branch; avoids OOB tail)
#pragma unroll
      for (int j = 0; j < 8; j++) { U0[j] = pA0[j * 64]; U1[j] = pA1[j * 64]; }
    }
    F1_COMPUTE(V0, V1, (g + 1) * 8)
  }
#undef F1_COMPUTE

  const float sc = 1.f / 16384.f;
#pragma unroll
  for (int r = 0; r < 2; r++) {
#pragma unroll
    for (int kk = 0; kk < 5; kk++) {
      if (kk < 4 || kg == 0) {
        int k = kg + 4 * kk;
        float4* dst = (float4*)(Xw + ((size_t)((b * 128 + y0 + r) * 17 + k)) * 128 + 2 * cp);
        *dst = make_float4(a[r][kk][0].x * sc, a[r][kk][0].y * sc,
                           a[r][kk][1].x * sc, a[r][kk][1].y * sc);
      }
    }
  }
}

// ---------------- F2: Xf[b,hm,k,c] = sum_y Xw[b,y,k,c] e^{-i 2pi h y/128} ---
// Grid doubled (mode-split): each block handles 16 of the 32 hm modes
// (8 per thread) -> 1088 blocks, 4.25 waves/SIMD for latency hiding.
__global__ __launch_bounds__(256) void k_F2(
    const float2* __restrict__ Xw, float2* __restrict__ Xf) {
  __shared__ float2 tw[128];
  int t = threadIdx.x;
  if (t < 128) { float s, c; __sincosf(PI2 * t / 128.f, &s, &c); tw[t] = make_float2(c, s); }
  __syncthreads();
  const char* twc = (const char*)tw;
  int bk = blockIdx.x >> 1, mh = blockIdx.x & 1;
  int b = bk / 17, k = bk - b * 17;
  int c = t & 127, hh = t >> 7;
  int g = mh * 2 + hh;                    // mode group 0..3: hm = g*8 + q
  int h8[8];
#pragma unroll
  for (int q = 0; q < 8; q++) {
    int hm = g * 8 + q;
    h8[q] = (hm < 16 ? hm : hm + 96) * 8;
  }
  float2 acc[8];
#pragma unroll
  for (int q = 0; q < 8; q++) acc[q] = make_float2(0.f, 0.f);
  const float2* xp = Xw + ((size_t)(b * 128) * 17 + k) * 128 + c;
  for (int y = 0; y < 128; y++) {
    float2 xv = xp[(size_t)y * 2176];
#pragma unroll
    for (int q = 0; q < 8; q++) {
      int ob = (h8[q] * y) & 1016;
      float2 w = *(const float2*)(twc + ob);
      acc[q].x += xv.x * w.x + xv.y * w.y;
      acc[q].y += xv.y * w.x - xv.x * w.y;
    }
  }
  float2* op = Xf + ((size_t)(b * 32 + g * 8) * 17 + k) * 128 + c;
#pragma unroll
  for (int q = 0; q < 8; q++) op[(size_t)q * 2176] = acc[q];
}

// ---------------- spec (fused K): Y[b,m,i] = sum_j K[m,i,j] Xf[b,m,j] -------
// K[m,i,j] = sum_d S0[hm,i,j,d]*S1[w,i,j,d], computed in the staging step.
__global__ __launch_bounds__(256) void k_spec(
    const float4* __restrict__ S0, const float4* __restrict__ S1,
    const float2* __restrict__ Xf, float2* __restrict__ Y) {
  __shared__ float2 Xs[32][128];
  __shared__ float2 Ks[16][129];
  int m = blockIdx.x;
  int hm = m / 17, w = m - hm * 17;
  int t = threadIdx.x;
  for (int q = t; q < 32 * 128; q += 256) {
    int b = q >> 7, j = q & 127;
    Xs[b][j] = Xf[((size_t)(b * 32 + hm) * 17 + w) * 128 + j];
  }
  const float4* s0p = S0 + (size_t)hm * 16384;
  const float4* s1p = S1 + (size_t)w * 16384;
  int i = t & 127, bh = t >> 7;
  float2 acc[16];
#pragma unroll
  for (int bb = 0; bb < 16; bb++) acc[bb] = make_float2(0.f, 0.f);
  for (int jt = 0; jt < 128; jt += 16) {
    __syncthreads();
    for (int q = t; q < 16 * 128; q += 256) {
      int ii = q >> 4, jj = q & 15;
      float4 a = s0p[ii * 128 + jt + jj];
      float4 b4 = s1p[ii * 128 + jt + jj];
      Ks[jj][ii] = make_float2(a.x * b4.x - a.y * b4.y + a.z * b4.z - a.w * b4.w,
                               a.x * b4.y + a.y * b4.x + a.z * b4.w + a.w * b4.z);
    }
    __syncthreads();
#pragma unroll 4
    for (int jj = 0; jj < 16; jj++) {
      float2 kv = Ks[jj][i];
#pragma unroll
      for (int bb = 0; bb < 16; bb++) {
        float2 xv = Xs[bh * 16 + bb][jt + jj];
        acc[bb].x += kv.x * xv.x - kv.y * xv.y;
        acc[bb].y += kv.x * xv.y + kv.y * xv.x;
      }
    }
  }
#pragma unroll
  for (int bb = 0; bb < 16; bb++) {
    int b = bh * 16 + bb;
    Y[((size_t)(b * 32 + hm) * 17 + w) * 128 + i] = acc[bb];
  }
}

// ---------------- I1: Q[b,y,k,o] = sum_hm Y[b,hm,k,o] e^{+i 2pi h y/128} ----
// Grid doubled (y-split): each block covers 64 y (32 per thread) -> 1088
// blocks, reaching the VGPR-allowed ~4 waves/SIMD.
__global__ __launch_bounds__(256) void k_I1(
    const float2* __restrict__ Y, float2* __restrict__ Q) {
  __shared__ float2 tw[128];
  int t = threadIdx.x;
  if (t < 128) { float s, c; __sincosf(PI2 * t / 128.f, &s, &c); tw[t] = make_float2(c, s); }
  __syncthreads();
  const char* twc = (const char*)tw;
  int bk = blockIdx.x >> 1, yq = blockIdx.x & 1;
  int b = bk / 17, k = bk - b * 17;
  int o = t & 127, yh = t >> 7;
  int ybase = yq * 64 + yh * 32;
  float2 v[32];
#pragma unroll
  for (int hm = 0; hm < 32; hm++)
    v[hm] = Y[((size_t)(b * 32 + hm) * 17 + k) * 128 + o];
  float2* qp = Q + ((size_t)(b * 128) * 17 + k) * 128 + o;
  for (int yy = 0; yy < 32; yy++) {
    int y = ybase + yy;
    float2 a = make_float2(0.f, 0.f);
#pragma unroll
    for (int hm = 0; hm < 32; hm++) {
      const int h8 = (hm < 16 ? hm : hm + 96) * 8;
      int ob = (h8 * y) & 1016;
      float2 w = *(const float2*)(twc + ob);
      a.x += v[hm].x * w.x - v[hm].y * w.y;
      a.y += v[hm].x * w.y + v[hm].y * w.x;
    }
    qp[(size_t)y * 2176] = a;
  }
}

// ---------------- I2: out[b,y,x,o] = sum_k wk Re(Q[b,y,k,o] e^{+i 2pi kx/128})
// 2 y-rows per block; Q held in 2x17 complex registers (weight folded in).
__global__ __launch_bounds__(256) void k_I2(
    const float2* __restrict__ Q, float* __restrict__ out) {
  __shared__ float2 tw[128];
  int t = threadIdx.x;
  if (t < 128) { float s, c; __sincosf(PI2 * t / 128.f, &s, &c); tw[t] = make_float2(c, s); }
  __syncthreads();
  const char* twc = (const char*)tw;
  int b = blockIdx.x >> 6;
  int y0 = (blockIdx.x & 63) * 2;
  int o = t & 127, xh = t >> 7;
  const float2* q0p = Q + ((size_t)(b * 128 + y0) * 17) * 128 + o;
  float2 q0[17], q1[17];
#pragma unroll
  for (int k = 0; k < 17; k++) {
    float wgt = (k == 0) ? 1.f : 2.f;
    float2 v0 = q0p[k * 128];
    float2 v1 = q0p[2176 + k * 128];
    q0[k] = make_float2(v0.x * wgt, v0.y * wgt);
    q1[k] = make_float2(v1.x * wgt, v1.y * wgt);
  }
  float* o0 = out + ((size_t)(b * 128 + y0) * 128) * 128 + o;
  float* o1 = o0 + 16384;
  for (int xx = 0; xx < 64; xx++) {
    int x = xh * 64 + xx;
    float s0 = 0.f, s1 = 0.f;
#pragma unroll
    for (int k = 0; k < 17; k++) {
      int ob = (k * 8 * x) & 1016;
      float2 w = *(const float2*)(twc + ob);
      s0 += q0[k].x * w.x - q0[k].y * w.y;
      s1 += q1[k].x * w.x - q1[k].y * w.y;
    }
    o0[x * 128] = s0;
    o1[x * 128] = s1;
  }
}

extern "C" void kernel_launch(void* const* d_in, const int* in_sizes, int n_in,
                              void* d_out, int out_size, void* d_ws, size_t ws_size,
                              hipStream_t stream) {
  (void)in_sizes; (void)n_in; (void)out_size;
  const float*  X     = (const float*)d_in[0];
  const float2* kout0 = (const float2*)d_in[1];
  const float2* kin0  = (const float2*)d_in[2];
  const float2* kout1 = (const float2*)d_in[3];
  const float2* kin1  = (const float2*)d_in[4];
  float* out = (float*)d_out;

  // Workspace (float2 units): A (Xw, reused as Q) | S0 | S1 | Xf | Y  = ~120 MB
  float2* ws = (float2*)d_ws;
  const size_t NA = 8912896;                 // 32*128*17*128
  float2* A  = ws;
  float2* S0 = ws + NA;                      // 1,048,576 f2 (as float4: 524,288)
  float2* S1 = S0 + 1048576;                 //   557,056 f2
  float2* Xf = S1 + 557056;                  // 2,228,224 f2
  float2* Yk = Xf + 2228224;                 // 2,228,224 f2
  const size_t need = (NA + 1048576 + 557056 + 2 * 2228224) * sizeof(float2);
  if (ws_size < need) return;

  k_S   <<<49 * 128, 128, 0, stream>>>(kout0, kin0, kout1, kin1,
                                       (float4*)S0, (float4*)S1);
  k_F1  <<<32 * 64, 256, 0, stream>>>(X, A);
  k_F2  <<<32 * 17 * 2, 256, 0, stream>>>(A, Xf);
  k_spec<<<544, 256, 0, stream>>>((const float4*)S0, (const float4*)S1, Xf, Yk);
  k_I1  <<<32 * 17 * 2, 256, 0, stream>>>(Yk, A);
  k_I2  <<<32 * 64, 256, 0, stream>>>(A, out);
}

// Round 5
// 924.578 us; speedup vs baseline: 1.2026x; 1.0205x over previous
//
#include <hip/hip_runtime.h>
#include <math.h>

#define PI2 6.283185307179586f

// B=32, H=128, W=128, C=128; hm modes 32 (rows 0..15,112..127), k modes 17
// Layouts (float2 = complex):
//  kout0/kin0: [32][128][2][64]; kout1/kin1: [17][128][2][64]
//  S0: [32][128][128]{d0,d1} as float4   S1: [17][128][128] float4
//  Xw/Q: [32][128][17][128] f2   Xf/Y: [32][32][17][128] f2

// ---------------- S build: S[s,i,j,d] = sum_r ko[s,i,d,r]*ki[s,j,d,r] -------
__global__ __launch_bounds__(128) void k_S(
    const float2* __restrict__ ko0, const float2* __restrict__ ki0,
    const float2* __restrict__ ko1, const float2* __restrict__ ki1,
    float4* __restrict__ S0, float4* __restrict__ S1) {
  int bid = blockIdx.x;
  int s = bid >> 7;      // 0..48
  int i = bid & 127;
  int j = threadIdx.x;   // 128 threads
  const float2* ko; const float2* ki; float4* S; int si;
  if (s < 32) { ko = ko0; ki = ki0; S = S0; si = s; }
  else        { ko = ko1; ki = ki1; S = S1; si = s - 32; }
  __shared__ float2 koS[2][64];
  koS[j >> 6][j & 63] = ko[(si * 128 + i) * 128 + j];
  __syncthreads();
  const float2* kirow = ki + (si * 128 + j) * 128;
  float2 acc[2];
#pragma unroll
  for (int d = 0; d < 2; d++) {
    float2 a2 = make_float2(0.f, 0.f);
    for (int r = 0; r < 64; r++) {
      float2 a = koS[d][r];
      float2 b = kirow[d * 64 + r];
      a2.x += a.x * b.x - a.y * b.y;
      a2.y += a.x * b.y + a.y * b.x;
    }
    acc[d] = a2;
  }
  S[(si * 128 + i) * 128 + j] = make_float4(acc[0].x, acc[0].y, acc[1].x, acc[1].y);
}

// ---------------- F1: Xw[b,y,k,c] = sc * sum_x X[b,y,x,c] e^{-i 2pi kx/128} -
// (R4 winner, unchanged) c-pair per thread; k 4-way wave split; ping-pong
// register prefetch; (cos,-sin) table for pk-fma accumulate shape.
__global__ __launch_bounds__(256) void k_F1(
    const float* __restrict__ X, float2* __restrict__ Xw) {
  __shared__ float2 tw[256];                  // (cos, -sin), period-128 doubled
  int t = threadIdx.x;
  int cp = t & 63, kg = t >> 6;               // kg wave-uniform (4 groups)
  int b = blockIdx.x >> 6;
  int y0 = (blockIdx.x & 63) * 2;
  const float2* pA0 = (const float2*)X + ((size_t)(b * 128 + y0) * 128) * 64 + cp;
  const float2* pA1 = pA0 + 8192;             // row y0+1
  const float2* pB0 = pA0 + 512;              // group g+1
  const float2* pB1 = pA1 + 512;

  float2 U0[8], U1[8], V0[8], V1[8];
#pragma unroll
  for (int j = 0; j < 8; j++) { U0[j] = pA0[j * 64]; U1[j] = pA1[j * 64]; }

  if (t < 128) {
    float s, c; __sincosf(PI2 * t / 128.f, &s, &c);
    tw[t] = make_float2(c, -s);
    tw[t + 128] = make_float2(c, -s);
  }
  __syncthreads();
  const char* twc = (const char*)tw;

  float2 a[2][5][2];
#pragma unroll
  for (int r = 0; r < 2; r++)
#pragma unroll
    for (int kk = 0; kk < 5; kk++) {
      a[r][kk][0] = make_float2(0.f, 0.f);
      a[r][kk][1] = make_float2(0.f, 0.f);
    }

#define F1_COMPUTE(B0, B1, xs)                                            \
  {                                                                       \
    _Pragma("unroll")                                                     \
    for (int kk = 0; kk < 4; kk++) {                                      \
      int k8 = kg * 8 + 32 * kk;                                          \
      int ob = (k8 * (xs)) & 1016;                                        \
      _Pragma("unroll")                                                   \
      for (int j = 0; j < 8; j++) {                                       \
        float2 w = *(const float2*)(twc + ob + j * k8);                   \
        a[0][kk][0].x += B0[j].x * w.x; a[0][kk][0].y += B0[j].x * w.y;   \
        a[0][kk][1].x += B0[j].y * w.x; a[0][kk][1].y += B0[j].y * w.y;   \
        a[1][kk][0].x += B1[j].x * w.x; a[1][kk][0].y += B1[j].x * w.y;   \
        a[1][kk][1].x += B1[j].y * w.x; a[1][kk][1].y += B1[j].y * w.y;   \
      }                                                                   \
    }                                                                     \
    if (kg == 0) { /* wave-uniform: only wave 0 runs k=16 */              \
      int ob = (128 * (xs)) & 1016;                                       \
      _Pragma("unroll")                                                   \
      for (int j = 0; j < 8; j++) {                                       \
        float2 w = *(const float2*)(twc + ob + j * 128);                  \
        a[0][4][0].x += B0[j].x * w.x; a[0][4][0].y += B0[j].x * w.y;     \
        a[0][4][1].x += B0[j].y * w.x; a[0][4][1].y += B0[j].y * w.y;     \
        a[1][4][0].x += B1[j].x * w.x; a[1][4][0].y += B1[j].x * w.y;     \
        a[1][4][1].x += B1[j].y * w.x; a[1][4][1].y += B1[j].y * w.y;     \
      }                                                                   \
    }                                                                     \
  }

  for (int g = 0; g < 16; g += 2) {
#pragma unroll
    for (int j = 0; j < 8; j++) { V0[j] = pB0[j * 64]; V1[j] = pB1[j * 64]; }
    F1_COMPUTE(U0, U1, g * 8)
    pA0 += 1024; pA1 += 1024; pB0 += 1024; pB1 += 1024;
    if (g < 14) {
#pragma unroll
      for (int j = 0; j < 8; j++) { U0[j] = pA0[j * 64]; U1[j] = pA1[j * 64]; }
    }
    F1_COMPUTE(V0, V1, (g + 1) * 8)
  }
#undef F1_COMPUTE

  const float sc = 1.f / 16384.f;
#pragma unroll
  for (int r = 0; r < 2; r++) {
#pragma unroll
    for (int kk = 0; kk < 5; kk++) {
      if (kk < 4 || kg == 0) {
        int k = kg + 4 * kk;
        float4* dst = (float4*)(Xw + ((size_t)((b * 128 + y0 + r) * 17 + k)) * 128 + 2 * cp);
        *dst = make_float4(a[r][kk][0].x * sc, a[r][kk][0].y * sc,
                           a[r][kk][1].x * sc, a[r][kk][1].y * sc);
      }
    }
  }
}

// ---------------- F2: Xf[b,hm,k,c] = sum_y Xw[b,y,k,c] e^{-i 2pi h y/128} ---
// float4 twiddle (c,-s,s,c): acc.xy += xv.x*w.xy + xv.y*w.zw  (2 pk-fma)
// + 8-deep ping-pong register prefetch of the strided global reads.
__global__ __launch_bounds__(256) void k_F2(
    const float2* __restrict__ Xw, float2* __restrict__ Xf) {
  __shared__ float4 tw[128];   // (cos, -sin, sin, cos)
  int t = threadIdx.x;
  int bk = blockIdx.x >> 1, mh = blockIdx.x & 1;
  int b = bk / 17, k = bk - b * 17;
  int c = t & 127, hh = t >> 7;
  int g = mh * 2 + hh;                    // mode group 0..3: hm = g*8 + q
  const float2* xp = Xw + ((size_t)(b * 128) * 17 + k) * 128 + c;

  // prologue: issue group-0 loads before LDS init/barrier
  float2 U[8], V[8];
#pragma unroll
  for (int j = 0; j < 8; j++) U[j] = xp[(size_t)j * 2176];

  if (t < 128) {
    float s, cc; __sincosf(PI2 * t / 128.f, &s, &cc);
    tw[t] = make_float4(cc, -s, s, cc);
  }
  __syncthreads();
  const char* twc = (const char*)tw;

  int h16[8];
#pragma unroll
  for (int q = 0; q < 8; q++) {
    int hm = g * 8 + q;
    h16[q] = (hm < 16 ? hm : hm + 96) * 16;
  }
  float2 acc[8];
#pragma unroll
  for (int q = 0; q < 8; q++) acc[q] = make_float2(0.f, 0.f);

  // (h16*y)&2032 == ((h*y)&127)*16  (mask of a 16-scaled index)
#define F2_COMPUTE(BUF, ys)                                               \
  _Pragma("unroll")                                                       \
  for (int j = 0; j < 8; j++) {                                           \
    float2 xv = BUF[j];                                                   \
    _Pragma("unroll")                                                     \
    for (int q = 0; q < 8; q++) {                                         \
      float4 w = *(const float4*)(twc + ((h16[q] * ((ys) + j)) & 2032));  \
      acc[q].x += xv.x * w.x; acc[q].y += xv.x * w.y;                     \
      acc[q].x += xv.y * w.z; acc[q].y += xv.y * w.w;                     \
    }                                                                     \
  }

  for (int yg = 0; yg < 16; yg += 2) {
#pragma unroll
    for (int j = 0; j < 8; j++) V[j] = xp[(size_t)((yg + 1) * 8 + j) * 2176];
    F2_COMPUTE(U, yg * 8)
    if (yg < 14) {
#pragma unroll
      for (int j = 0; j < 8; j++) U[j] = xp[(size_t)((yg + 2) * 8 + j) * 2176];
    }
    F2_COMPUTE(V, (yg + 1) * 8)
  }
#undef F2_COMPUTE

  float2* op = Xf + ((size_t)(b * 32 + g * 8) * 17 + k) * 128 + c;
#pragma unroll
  for (int q = 0; q < 8; q++) op[(size_t)q * 2176] = acc[q];
}

// ---------------- spec (fused K): Y[b,m,i] = sum_j K[m,i,j] Xf[b,m,j] -------
// K[m,i,j] = sum_d S0[hm,i,j,d]*S1[w,i,j,d], computed in the staging step.
__global__ __launch_bounds__(256) void k_spec(
    const float4* __restrict__ S0, const float4* __restrict__ S1,
    const float2* __restrict__ Xf, float2* __restrict__ Y) {
  __shared__ float2 Xs[32][128];
  __shared__ float2 Ks[16][129];
  int m = blockIdx.x;
  int hm = m / 17, w = m - hm * 17;
  int t = threadIdx.x;
  for (int q = t; q < 32 * 128; q += 256) {
    int b = q >> 7, j = q & 127;
    Xs[b][j] = Xf[((size_t)(b * 32 + hm) * 17 + w) * 128 + j];
  }
  const float4* s0p = S0 + (size_t)hm * 16384;
  const float4* s1p = S1 + (size_t)w * 16384;
  int i = t & 127, bh = t >> 7;
  float2 acc[16];
#pragma unroll
  for (int bb = 0; bb < 16; bb++) acc[bb] = make_float2(0.f, 0.f);
  for (int jt = 0; jt < 128; jt += 16) {
    __syncthreads();
    for (int q = t; q < 16 * 128; q += 256) {
      int ii = q >> 4, jj = q & 15;
      float4 a = s0p[ii * 128 + jt + jj];
      float4 b4 = s1p[ii * 128 + jt + jj];
      Ks[jj][ii] = make_float2(a.x * b4.x - a.y * b4.y + a.z * b4.z - a.w * b4.w,
                               a.x * b4.y + a.y * b4.x + a.z * b4.w + a.w * b4.z);
    }
    __syncthreads();
#pragma unroll 4
    for (int jj = 0; jj < 16; jj++) {
      float2 kv = Ks[jj][i];
#pragma unroll
      for (int bb = 0; bb < 16; bb++) {
        float2 xv = Xs[bh * 16 + bb][jt + jj];
        acc[bb].x += kv.x * xv.x - kv.y * xv.y;
        acc[bb].y += kv.x * xv.y + kv.y * xv.x;
      }
    }
  }
#pragma unroll
  for (int bb = 0; bb < 16; bb++) {
    int b = bh * 16 + bb;
    Y[((size_t)(b * 32 + hm) * 17 + w) * 128 + i] = acc[bb];
  }
}

// ---------------- I1: Q[b,y,k,o] = sum_hm Y[b,hm,k,o] e^{+i 2pi h y/128} ----
// float4 twiddle (c,s,-s,c): a.xy += v.x*w.xy + v.y*w.zw  (2 pk-fma);
// Y preloads issued before the LDS init/barrier.
__global__ __launch_bounds__(256) void k_I1(
    const float2* __restrict__ Y, float2* __restrict__ Q) {
  __shared__ float4 tw[128];   // (cos, sin, -sin, cos)
  int t = threadIdx.x;
  int bk = blockIdx.x >> 1, yq = blockIdx.x & 1;
  int b = bk / 17, k = bk - b * 17;
  int o = t & 127, yh = t >> 7;
  int ybase = yq * 64 + yh * 32;
  float2 v[32];
#pragma unroll
  for (int hm = 0; hm < 32; hm++)
    v[hm] = Y[((size_t)(b * 32 + hm) * 17 + k) * 128 + o];
  if (t < 128) {
    float s, cc; __sincosf(PI2 * t / 128.f, &s, &cc);
    tw[t] = make_float4(cc, s, -s, cc);
  }
  __syncthreads();
  const char* twc = (const char*)tw;
  float2* qp = Q + ((size_t)(b * 128) * 17 + k) * 128 + o;
  for (int yy = 0; yy < 32; yy++) {
    int y = ybase + yy;
    float2 a = make_float2(0.f, 0.f);
#pragma unroll
    for (int hm = 0; hm < 32; hm++) {
      const int h16 = (hm < 16 ? hm : hm + 96) * 16;
      float4 w = *(const float4*)(twc + ((h16 * y) & 2032));
      a.x += v[hm].x * w.x; a.y += v[hm].x * w.y;
      a.x += v[hm].y * w.z; a.y += v[hm].y * w.w;
    }
    qp[(size_t)y * 2176] = a;
  }
}

// ---------------- I2: out[b,y,x,o] = sum_k wk Re(Q[b,y,k,o] e^{+i 2pi kx/128})
// 2 y-rows per block; rows packed into float2 accumulators:
// (s0,s1) += (q0.x,q1.x)*w.x + (-q0.y,-q1.y)*w.y  (2 pk-fma per k).
__global__ __launch_bounds__(256) void k_I2(
    const float2* __restrict__ Q, float* __restrict__ out) {
  __shared__ float2 tw[128];
  int t = threadIdx.x;
  int b = blockIdx.x >> 6;
  int y0 = (blockIdx.x & 63) * 2;
  int o = t & 127, xh = t >> 7;
  const float2* q0p = Q + ((size_t)(b * 128 + y0) * 17) * 128 + o;
  float2 qre[17], qmi[17];
#pragma unroll
  for (int k = 0; k < 17; k++) {
    float wgt = (k == 0) ? 1.f : 2.f;
    float2 v0 = q0p[k * 128];
    float2 v1 = q0p[2176 + k * 128];
    qre[k] = make_float2(v0.x * wgt, v1.x * wgt);
    qmi[k] = make_float2(-v0.y * wgt, -v1.y * wgt);
  }
  if (t < 128) { float s, c; __sincosf(PI2 * t / 128.f, &s, &c); tw[t] = make_float2(c, s); }
  __syncthreads();
  const char* twc = (const char*)tw;
  float* o0 = out + ((size_t)(b * 128 + y0) * 128) * 128 + o;
  float* o1 = o0 + 16384;
  for (int xx = 0; xx < 64; xx++) {
    int x = xh * 64 + xx;
    float2 r = make_float2(0.f, 0.f);
#pragma unroll
    for (int k = 0; k < 17; k++) {
      float2 w = *(const float2*)(twc + ((k * 8 * x) & 1016));
      r.x += qre[k].x * w.x; r.y += qre[k].y * w.x;
      r.x += qmi[k].x * w.y; r.y += qmi[k].y * w.y;
    }
    o0[x * 128] = r.x;
    o1[x * 128] = r.y;
  }
}

extern "C" void kernel_launch(void* const* d_in, const int* in_sizes, int n_in,
                              void* d_out, int out_size, void* d_ws, size_t ws_size,
                              hipStream_t stream) {
  (void)in_sizes; (void)n_in; (void)out_size;
  const float*  X     = (const float*)d_in[0];
  const float2* kout0 = (const float2*)d_in[1];
  const float2* kin0  = (const float2*)d_in[2];
  const float2* kout1 = (const float2*)d_in[3];
  const float2* kin1  = (const float2*)d_in[4];
  float* out = (float*)d_out;

  // Workspace (float2 units): A (Xw, reused as Q) | S0 | S1 | Xf | Y  = ~120 MB
  float2* ws = (float2*)d_ws;
  const size_t NA = 8912896;                 // 32*128*17*128
  float2* A  = ws;
  float2* S0 = ws + NA;                      // 1,048,576 f2 (as float4: 524,288)
  float2* S1 = S0 + 1048576;                 //   557,056 f2
  float2* Xf = S1 + 557056;                  // 2,228,224 f2
  float2* Yk = Xf + 2228224;                 // 2,228,224 f2
  const size_t need = (NA + 1048576 + 557056 + 2 * 2228224) * sizeof(float2);
  if (ws_size < need) return;

  k_S   <<<49 * 128, 128, 0, stream>>>(kout0, kin0, kout1, kin1,
                                       (float4*)S0, (float4*)S1);
  k_F1  <<<32 * 64, 256, 0, stream>>>(X, A);
  k_F2  <<<32 * 17 * 2, 256, 0, stream>>>(A, Xf);
  k_spec<<<544, 256, 0, stream>>>((const float4*)S0, (const float4*)S1, Xf, Yk);
  k_I1  <<<32 * 17 * 2, 256, 0, stream>>>(Yk, A);
  k_I2  <<<32 * 64, 256, 0, stream>>>(A, out);
}